// Round 3
// baseline (175.447 us; speedup 1.0000x reference)
//
#include <hip/hip_runtime.h>
#include <hip/hip_bf16.h>

// Problem constants: B=64, Cin=3, H=W=64, O=16, k=7, fh=fw=58
#define O_ 16
#define CIN 3
#define KK 7
#define NTAP 49
#define NK 2352                   // O*CIN*49
#define NLIST 96                  // CIN * 2(hm) * O
#define PLANE 4096
#define NPLANES 192

#define VALID_PAIRS_B 215296.0f   // 3364 * 64  (valid pixels per tap * B)
#define INV_VISITED_B 2304.0f     // 36 * 64    (invalid pairs visited by bndrow role, per tap)

// interior geometry: px,py in [6,58) -> 52x52 = 2704 per plane
#define NINT_TOT 519168           // 2704 * 192
#define NI_BLOCKS 507             // 507*1024 == 519168 exactly (4 px/thread, 256 thr)
#define NBR_BLOCKS 576            // 12 bnd rows * 192 planes = 2304 waves / 4
#define NBC_BLOCKS 576            // 12 bnd cols * 192 planes = 2304 waves / 4

// output geometry
#define SEG 10092u                // fh*fh*Cin
#define OSEG 161472u              // O*SEG
#define OUT1 10334208u            // B*OSEG
#define NOUT (3u * OUT1)

// ws float offsets
#define WS_GSUM 0                 // 33 floats (pad 64): [0..16) SabsH_raw, [16..32) SabsM_raw, [32] Wtot
#define WS_SORT 64                // 96 lists * 64 (padded 1e30)
#define WS_PREF (64 + 6144)       // 96 lists * 64 : P'[j] = Ptot - 2*prefix[j]
#define WS_KST  (64 + 12288)     // 64: [KsumH|KabsH|KsumM|KabsM] x16

// ---------------------------------------------------------------------------
// prep: rank-sort the 96 (o,c,hm) 49-lists, build P' tables, K stats, zero gsum
// list id L = c*32 + hm*16 + o
// ---------------------------------------------------------------------------
__global__ __launch_bounds__(1024) void prep_kernel(
    const float* __restrict__ Kh, const float* __restrict__ Km,
    float* __restrict__ ws)
{
    __shared__ float sRaw[NLIST * NTAP];
    __shared__ float sSort[NLIST * 64];
    const int tid = threadIdx.x;

    for (int i = tid; i < NK; i += 1024) {
        int o = i / 147; int r = i - o * 147; int c = r / NTAP; int t = r - c * NTAP;
        sRaw[(c * 32 + o) * NTAP + t]      = Kh[i];
        sRaw[(c * 32 + 16 + o) * NTAP + t] = Km[i];
    }
    __syncthreads();

    // rank sort (ties broken by index -> permutation)
    for (int item = tid; item < NLIST * NTAP; item += 1024) {
        int L = item / NTAP; int i = item - L * NTAP;
        const float* lst = &sRaw[L * NTAP];
        float ki = lst[i];
        int rank = 0;
        for (int j = 0; j < NTAP; ++j) {
            float kj = lst[j];
            rank += (int)((kj < ki) || (kj == ki && j < i));
        }
        sSort[L * 64 + rank] = ki;
    }
    for (int item = tid; item < NLIST * 15; item += 1024) {
        int L = item / 15; int j = 49 + (item - L * 15);
        sSort[L * 64 + j] = 1e30f;
    }
    __syncthreads();

    float* wsort = ws + WS_SORT;
    float* wpref = ws + WS_PREF;
    for (int i = tid; i < NLIST * 64; i += 1024) wsort[i] = sSort[i];

    if (tid < NLIST) {
        const float* s = &sSort[tid * 64];
        float tot = 0.f;
        for (int j = 0; j < NTAP; ++j) tot += s[j];
        float run = 0.f;
        float* p = wpref + tid * 64;
        for (int j = 0; j <= NTAP; ++j) { p[j] = tot - 2.f * run; if (j < NTAP) run += s[j]; }
        for (int j = NTAP + 1; j < 64; ++j) p[j] = 0.f;
    }
    if (tid >= 128 && tid < 192) {
        int t2 = tid - 128; int o = t2 & 15; int which = t2 >> 4;
        const float* src = (which < 2) ? Kh : Km;
        bool isAbs = (which & 1);
        float s = 0.f;
        for (int t = 0; t < 147; ++t) {
            float a = src[o * 147 + t];
            s += isAbs ? fabsf(a) : a;
        }
        ws[WS_KST + t2] = s;
    }
    if (tid < 33) ws[WS_GSUM + tid] = 0.f;
}

// ---------------------------------------------------------------------------
__device__ __forceinline__ void reduce_and_atomic(float* ah, float* am, float wsum,
                                                  float* gsum, float (*sred)[33])
{
    const int lane = threadIdx.x & 63;
    const int wid  = threadIdx.x >> 6;
#pragma unroll
    for (int o = 0; o < O_; ++o) {
        float h = ah[o], m = am[o];
#pragma unroll
        for (int off = 32; off > 0; off >>= 1) {
            h += __shfl_down(h, off);
            m += __shfl_down(m, off);
        }
        if (lane == 0) { sred[wid][o] = h; sred[wid][16 + o] = m; }
    }
    float s = wsum;
#pragma unroll
    for (int off = 32; off > 0; off >>= 1) s += __shfl_down(s, off);
    if (lane == 0) sred[wid][32] = s;
    __syncthreads();
    if (threadIdx.x < 33) {
        float t = sred[0][threadIdx.x] + sred[1][threadIdx.x] +
                  sred[2][threadIdx.x] + sred[3][threadIdx.x];
        atomicAdd(&gsum[threadIdx.x], t);
    }
}

// ---------------------------------------------------------------------------
// sum kernel: 3 block roles.
//  interior  : binary search per (pixel, o, hm) over sorted 49-lists
//  bnd rows  : wave = one boundary row; dy-range uniform, x masked via vv=0
//  bnd cols  : wave = one boundary col over interior rows; dx-range uniform, no masks
// ---------------------------------------------------------------------------
__global__ __launch_bounds__(256) void sum_kernel(
    const float* __restrict__ x,
    const float* __restrict__ Kh, const float* __restrict__ Km,
    float* __restrict__ ws)
{
    __shared__ float4 sh4[3072];      // 49.2 KB
    __shared__ float sred[4][33];
    float* shf  = (float*)sh4;
    float* gsum = ws + WS_GSUM;

    float ah[O_], am[O_];
#pragma unroll
    for (int o = 0; o < O_; ++o) { ah[o] = 0.f; am[o] = 0.f; }
    float wsum = 0.f;

    if (blockIdx.x < NI_BLOCKS) {
        // ---- interior ----
        const float4* wsrc = (const float4*)(ws + WS_SORT);  // sorted + pref contiguous
        for (int i = threadIdx.x; i < 3072; i += 256) sh4[i] = wsrc[i];
        __syncthreads();
        const float* sSort = shf;
        const float* sPref = shf + 6144;

        const unsigned g0 = blockIdx.x * 1024u + threadIdx.x;
        float v[4]; int lbase[4];
#pragma unroll
        for (int p = 0; p < 4; ++p) {
            unsigned g = g0 + p * 256u;
            unsigned plane = g / 2704u;
            unsigned i = g - plane * 2704u;
            unsigned ry = i / 52u;
            unsigned rx = i - ry * 52u;
            v[p] = x[plane * 4096u + (ry + 6u) * 64u + (rx + 6u)];
            unsigned c = plane - (plane / 3u) * 3u;
            lbase[p] = (int)(c * 32u) * 64;
        }
        wsum = 49.f * (v[0] + v[1] + v[2] + v[3]);

#pragma unroll 2
        for (int o = 0; o < O_; ++o) {
#pragma unroll
            for (int p = 0; p < 4; ++p) {
                {   // hit list
                    int base = lbase[p] + o * 64;
                    int pos = 0;
#pragma unroll
                    for (int s = 32; s > 0; s >>= 1) {
                        float probe = sSort[base + pos + s - 1];
                        if (probe < v[p]) pos += s;
                    }
                    ah[o] += fmaf(v[p], 2.f * (float)pos - 49.f, sPref[base + pos]);
                }
                {   // miss list
                    int base = lbase[p] + (16 + o) * 64;
                    int pos = 0;
#pragma unroll
                    for (int s = 32; s > 0; s >>= 1) {
                        float probe = sSort[base + pos + s - 1];
                        if (probe < v[p]) pos += s;
                    }
                    am[o] += fmaf(v[p], 2.f * (float)pos - 49.f, sPref[base + pos]);
                }
            }
        }
    } else if (blockIdx.x < NI_BLOCKS + NBR_BLOCKS) {
        // ---- boundary rows ----
        for (int i = threadIdx.x; i < NK; i += 256) {
            int o = i / 147; int r = i - o * 147; int c = r / NTAP; int t = r - c * NTAP;
            shf[(c * NTAP + t) * 32 + 2 * o]     = Kh[i];
            shf[(c * NTAP + t) * 32 + 2 * o + 1] = Km[i];
        }
        __syncthreads();
        const int wid  = threadIdx.x >> 6;
        const int lane = threadIdx.x & 63;
        const int widx = (blockIdx.x - NI_BLOCKS) * 4 + wid;
        const int plane = widx / 12;
        const int r = widx - plane * 12;
        const int py = (r < 6) ? r : r + 52;          // rows 0..5, 58..63
        const int c = plane % 3;
        const int ay = (py < 6) ? 0 : py - 57;
        const int by = (py < 6) ? py + 1 : 7;
        const float v0 = x[plane * 4096 + py * 64 + lane];
        const int wx = min(min(lane + 1, 7), 64 - lane);
        wsum = v0 * (float)((by - ay) * wx);
        for (int dy = ay; dy < by; ++dy) {
            for (int dx = 0; dx < 7; ++dx) {
                bool okx = ((unsigned)(lane - dx)) < 58u;
                float vv = okx ? v0 : 0.f;            // invalid -> |k| , corrected in fill
                const float4* q = &sh4[(c * NTAP + dy * KK + dx) * 8];
#pragma unroll
                for (int j = 0; j < 8; ++j) {
                    float4 kq = q[j];
                    ah[2 * j]     += fabsf(kq.x - vv);
                    am[2 * j]     += fabsf(kq.y - vv);
                    ah[2 * j + 1] += fabsf(kq.z - vv);
                    am[2 * j + 1] += fabsf(kq.w - vv);
                }
            }
        }
    } else {
        // ---- boundary cols over interior rows ----
        for (int i = threadIdx.x; i < NK; i += 256) {
            int o = i / 147; int r = i - o * 147; int c = r / NTAP; int t = r - c * NTAP;
            shf[(c * NTAP + t) * 32 + 2 * o]     = Kh[i];
            shf[(c * NTAP + t) * 32 + 2 * o + 1] = Km[i];
        }
        __syncthreads();
        const int wid  = threadIdx.x >> 6;
        const int lane = threadIdx.x & 63;
        const int widx = (blockIdx.x - NI_BLOCKS - NBR_BLOCKS) * 4 + wid;
        const int plane = widx / 12;
        const int j = widx - plane * 12;
        const int px = (j < 6) ? j : j + 52;          // cols 0..5, 58..63
        const int c = plane % 3;
        const int ax = (px < 6) ? 0 : px - 57;
        const int bx = (px < 6) ? px + 1 : 7;
        if (lane < 52) {
            const float v0 = x[plane * 4096 + (6 + lane) * 64 + px];
            wsum = v0 * (float)(7 * (bx - ax));
            for (int dx = ax; dx < bx; ++dx) {
                for (int dy = 0; dy < 7; ++dy) {
                    const float4* q = &sh4[(c * NTAP + dy * KK + dx) * 8];
#pragma unroll
                    for (int jj = 0; jj < 8; ++jj) {
                        float4 kq = q[jj];
                        ah[2 * jj]     += fabsf(kq.x - v0);
                        am[2 * jj]     += fabsf(kq.y - v0);
                        ah[2 * jj + 1] += fabsf(kq.z - v0);
                        am[2 * jj + 1] += fabsf(kq.w - v0);
                    }
                }
            }
        }
    }
    __syncthreads();
    reduce_and_atomic(ah, am, wsum, gsum, sred);
}

// ---------------------------------------------------------------------------
// fill: fold finalize into prologue, then broadcast-fill (write roofline).
//  s_hit  = -0.5*((215296*KsumH - Wtot) + (SabsH_raw - 2304*KabsH))
//  s_miss =  0.5*((Wtot - 215296*KsumM) + (SabsM_raw - 2304*KabsM))
// ---------------------------------------------------------------------------
__global__ __launch_bounds__(256) void fill_kernel(
    const float* __restrict__ ws,
    float4* __restrict__ out, unsigned n4)
{
    __shared__ float sv[48];
    if (threadIdx.x < 48) {
        int o   = threadIdx.x & 15;
        int grp = threadIdx.x >> 4;
        float KsumH = ws[WS_KST + o];
        float KabsH = ws[WS_KST + 16 + o];
        float KsumM = ws[WS_KST + 32 + o];
        float KabsM = ws[WS_KST + 48 + o];
        float Wtot  = ws[WS_GSUM + 32];
        float SabsH = ws[WS_GSUM + o]      - INV_VISITED_B * KabsH;
        float SabsM = ws[WS_GSUM + 16 + o] - INV_VISITED_B * KabsM;
        float s_hit  = -0.5f * ((VALID_PAIRS_B * KsumH - Wtot) + SabsH);
        float s_miss =  0.5f * ((Wtot - VALID_PAIRS_B * KsumM) + SabsM);
        sv[threadIdx.x] = (grp == 0) ? (s_hit - s_miss) : ((grp == 1) ? s_hit : s_miss);
    }
    __syncthreads();

    unsigned stride = gridDim.x * blockDim.x;
    for (unsigned i = blockIdx.x * blockDim.x + threadIdx.x; i < n4; i += stride) {
        unsigned fbase = i * 4u;
        unsigned w   = fbase / OUT1;
        unsigned rem = fbase - w * OUT1;
        unsigned o   = (rem % OSEG) / SEG;
        float val = sv[w * O_ + o];
        out[i] = make_float4(val, val, val, val);
    }
}

extern "C" void kernel_launch(void* const* d_in, const int* in_sizes, int n_in,
                              void* d_out, int out_size, void* d_ws, size_t ws_size,
                              hipStream_t stream)
{
    const float* x  = (const float*)d_in[0];
    const float* Kh = (const float*)d_in[1];
    const float* Km = (const float*)d_in[2];
    float* out = (float*)d_out;
    float* wsf = (float*)d_ws;

    prep_kernel<<<1, 1024, 0, stream>>>(Kh, Km, wsf);
    sum_kernel<<<NI_BLOCKS + NBR_BLOCKS + NBC_BLOCKS, 256, 0, stream>>>(x, Kh, Km, wsf);
    fill_kernel<<<4096, 256, 0, stream>>>(wsf, (float4*)out, NOUT / 4u);
}